// Round 7
// baseline (165.394 us; speedup 1.0000x reference)
//
#include <hip/hip_runtime.h>
#include <hip/hip_bf16.h>

constexpr int B = 256, S = 1024, T = 64;
constexpr float LOG2E = 1.4426950408889634f;
constexpr float LN2   = 0.6931471805599453f;

typedef _Float16 h2 __attribute__((ext_vector_type(2)));

static __device__ __forceinline__ float dot2f(unsigned int abits, h2 b, float c) {
    return __builtin_amdgcn_fdot2(__builtin_bit_cast(h2, abits), b, c, false);
}
static __device__ __forceinline__ unsigned int pack2(float lo, float hi) {
    return __builtin_bit_cast(unsigned int, __builtin_amdgcn_cvt_pkrtz(lo, hi));
}
// value from lane^1 via DPP quad_perm(1,0,3,2) — VALU speed, no LDS pipe
static __device__ __forceinline__ float xor1_dpp(float x) {
    return __int_as_float(__builtin_amdgcn_update_dpp(
        __float_as_int(x), __float_as_int(x), 0xB1, 0xF, 0xF, true));
}

// One wave per (chain, direction). dir=0: forward a-chain; dir=1: backward u-chain.
// Both run the IDENTICAL step: p <- e^{x} * (Wfrag-matvec p); only W layout and
// x indexing differ (data, not code).
__global__ __launch_bounds__(64) void crf_half(
        const float* __restrict__ emis, const int* __restrict__ tags,
        const float* __restrict__ U,    const float* __restrict__ bs,
        const float* __restrict__ be,   float* __restrict__ pvec,
        float* __restrict__ cvec,       float* __restrict__ pevec) {
    const int bid = blockIdx.x;
    const int chain = bid >> 1, dir = bid & 1;
    const int j = threadIdx.x;
    const float* eb = emis + (size_t)chain * (S * T);
    const int*   tb = tags + (size_t)chain * S;

    // W fragments: dir0 column j of W=e^U (pairs over i); dir1 row j of W.
    const float* Up   = U + (dir ? j * T : j);
    const int    ustep = dir ? 1 : T;
    h2 Wh[32];
#pragma unroll
    for (int m = 0; m < 32; ++m) {
        float w0 = __builtin_amdgcn_exp2f(Up[(2 * m)     * ustep] * LOG2E);
        float w1 = __builtin_amdgcn_exp2f(Up[(2 * m + 1) * ustep] * LOG2E);
        Wh[m] = __builtin_bit_cast(h2, pack2(w0, w1));
    }

    // ---- path energy: dir0 covers s in [0,512), dir1 [512,1024) ----
    float pe = 0.f;
#pragma unroll
    for (int c = 0; c < 8; ++c) {
        int s  = dir * 512 + c * 64 + j;
        int tg = tb[s];
        float e = eb[s * T + tg];
        if (s == 0)     e += bs[tg];
        if (s == S - 1) e += be[tg];
        pe += e;
        if (s < S - 1)  pe += U[tg * T + tb[s + 1]];
    }
#pragma unroll
    for (int m = 1; m < 64; m <<= 1) pe += __shfl_xor(pe, m, 64);

    // ---- init: dir0 p=a_0, dir1 p=u_1023=e^{x_1023} ----
    float x0 = dir ? (eb[(size_t)(S - 1) * T + j] + be[j]) : (eb[j] + bs[j]);
    float a0 = x0 * LOG2E;
    float M0 = a0;
#pragma unroll
    for (int m = 1; m < 64; m <<= 1) M0 = fmaxf(M0, __shfl_xor(M0, m, 64));
    float p   = __builtin_amdgcn_exp2f(a0 - M0);
    int   c2i = 0;
    const float c2f = M0;

    // slot u -> time index: dir0 t=1+u (u=0..510; u=511 is the extra plain matvec, x=0)
    //                       dir1 t=1022-u (u=0..510)
    const int tbase = dir ? 1022 : 1;
    const int tstep = dir ? -1 : 1;
    const int cnt   = dir ? 511 : 512;

    auto xld = [&](int u) {
        int uu = u < 511 ? u : 511;
        float v = eb[(size_t)(tbase + tstep * uu) * T + j];
        return u < 511 ? v : 0.0f;
    };
    auto step = [&](float xval) {
        float ex = __builtin_amdgcn_exp2f(xval * LOG2E);   // off critical chain
        float ph = xor1_dpp(p);
        unsigned int qb = pack2(p, ph);                    // even lane 2i: (p_2i, p_2i+1)
        float s0 = 0.f, s1 = 0.f, s2 = 0.f, s3 = 0.f;
#pragma unroll
        for (int i = 0; i < 32; i += 4) {
            s0 = dot2f(__builtin_amdgcn_readlane(qb, 2 * (i + 0)), Wh[i + 0], s0);
            s1 = dot2f(__builtin_amdgcn_readlane(qb, 2 * (i + 1)), Wh[i + 1], s1);
            s2 = dot2f(__builtin_amdgcn_readlane(qb, 2 * (i + 2)), Wh[i + 2], s2);
            s3 = dot2f(__builtin_amdgcn_readlane(qb, 2 * (i + 3)), Wh[i + 3], s3);
        }
        float ss = (s0 + s1) + (s2 + s3);
        unsigned int sb = __builtin_amdgcn_readfirstlane(__float_as_uint(ss));
        int ebits = (int)((sb >> 23) & 0xFF);
        c2i += ebits - 127;
        float scale = __uint_as_float((unsigned int)(254 - ebits) << 23);
        p = ss * scale * ex;
    };

    // ---- 8-deep ping-pong prefetch; 31x16 + 8 unguarded + 8 guarded tail ----
    float xa[8], xb[8];
#pragma unroll
    for (int u = 0; u < 8; ++u) xa[u] = xld(u);
    int u0 = 0;
    for (int k = 0; k < 31; ++k) {                 // slots 0..495
#pragma unroll
        for (int v = 0; v < 8; ++v) xb[v] = xld(u0 + 8 + v);
#pragma unroll
        for (int v = 0; v < 8; ++v) step(xa[v]);
#pragma unroll
        for (int v = 0; v < 8; ++v) xa[v] = xld(u0 + 16 + v);
#pragma unroll
        for (int v = 0; v < 8; ++v) step(xb[v]);
        u0 += 16;
    }
    // u0 = 496; xa holds slots 496..503
#pragma unroll
    for (int v = 0; v < 8; ++v) xb[v] = xld(504 + v);   // xld(511) -> 0 (fwd's extra step)
#pragma unroll
    for (int v = 0; v < 8; ++v) step(xa[v]);            // 496..503 < cnt always
#pragma unroll
    for (int v = 0; v < 8; ++v) if (504 + v < cnt) step(xb[v]);  // fwd: 8, bwd: 7

    pvec[(size_t)(dir * B + chain) * T + j] = p;
    if (j == 0) {
        cvec [dir * B + chain] = c2f + (float)c2i;
        pevec[dir * B + chain] = pe;
    }
}

// free_e = ln2*(log2(sum_j pf_j*pb_j) + Cf + Cb); nll = free_e - (pe_f + pe_b)
__global__ __launch_bounds__(64) void crf_combine(
        const float* __restrict__ pvec, const float* __restrict__ cvec,
        const float* __restrict__ pevec, float* __restrict__ nll) {
    const int c = blockIdx.x, j = threadIdx.x;
    float v = pvec[(size_t)c * T + j] * pvec[(size_t)(B + c) * T + j];
#pragma unroll
    for (int m = 1; m < 64; m <<= 1) v += __shfl_xor(v, m, 64);
    if (j == 0) {
        float free_e = LN2 * (__builtin_amdgcn_logf(v) + cvec[c] + cvec[B + c]);
        nll[c] = free_e - (pevec[c] + pevec[B + c]);
    }
}

__global__ __launch_bounds__(256, 1) void crf_reduce(const float* __restrict__ nll,
                                                     float* __restrict__ out) {
    float v = nll[threadIdx.x];
#pragma unroll
    for (int m = 1; m < 64; m <<= 1) v += __shfl_xor(v, m, 64);
    __shared__ float acc[4];
    if ((threadIdx.x & 63) == 0) acc[threadIdx.x >> 6] = v;
    __syncthreads();
    if (threadIdx.x == 0) out[0] = (acc[0] + acc[1] + acc[2] + acc[3]) * (1.0f / B);
}

extern "C" void kernel_launch(void* const* d_in, const int* in_sizes, int n_in,
                              void* d_out, int out_size, void* d_ws, size_t ws_size,
                              hipStream_t stream) {
    const float* emis = (const float*)d_in[0];
    const int*   tags = (const int*)d_in[1];
    const float* U    = (const float*)d_in[2];
    const float* bs   = (const float*)d_in[3];
    const float* be   = (const float*)d_in[4];

    float* ws    = (float*)d_ws;
    float* pvec  = ws;                    // [2][B][T] = 32768 floats
    float* cvec  = ws + 2 * B * T;        // [2][B]    = 512
    float* pevec = cvec + 2 * B;          // [2][B]    = 512
    float* nll   = pevec + 2 * B;         // [B]       = 256

    crf_half<<<dim3(2 * B), dim3(64), 0, stream>>>(emis, tags, U, bs, be, pvec, cvec, pevec);
    crf_combine<<<dim3(B), dim3(64), 0, stream>>>(pvec, cvec, pevec, nll);
    crf_reduce<<<dim3(1), dim3(256), 0, stream>>>(nll, (float*)d_out);
}